// Round 1
// baseline (140.210 us; speedup 1.0000x reference)
//
#include <hip/hip_runtime.h>

// LinearInterpolation: out[b, j, c] = v[b,seg,c] + (v[b,seg+1,c]-v[b,seg,c])*t
// with seg/t derived from the (tiny) knot index array. BATCH=262144,
// NKNOTS=13, M = idx[last]-idx[0] = 48, channels=2.
//
// Memory-bound: write 100.7 MB + read 27.3 MB -> ~20 us at 6.3 TB/s.
// One thread handles one (batch, j-pair): float4 coalesced store, four
// float2 loads (L1-cached, 104 B footprint per batch).

__global__ __launch_bounds__(256)
void LinearInterpolation_20907900797406_kernel(
    const int* __restrict__ index,
    const float2* __restrict__ value,
    float4* __restrict__ out,
    int batch, int nk, int m) {
  __shared__ int   s_idx[32];
  __shared__ int   s_seg[64];
  __shared__ float s_t[64];

  const int tid = threadIdx.x;
  if (tid < nk) s_idx[tid] = index[tid];
  __syncthreads();
  if (tid < m) {
    // p = idx[0] + tid + 1; seg = searchsorted(idx, p, 'left') - 1
    //   = (#knots < p) - 1
    const int p = s_idx[0] + tid + 1;
    int cnt = 0;
    #pragma unroll 13
    for (int k = 0; k < nk; ++k) cnt += (s_idx[k] < p) ? 1 : 0;
    const int seg = cnt - 1;
    s_seg[tid] = seg;
    s_t[tid] = (float)(p - s_idx[seg]) / (float)(s_idx[seg + 1] - s_idx[seg]);
  }
  __syncthreads();

  const int half = m >> 1;  // j-pairs per batch (24)
  const long long gid = (long long)blockIdx.x * blockDim.x + tid;
  const long long total = (long long)batch * half;
  if (gid >= total) return;

  const int b  = (int)(gid / half);
  const int jp = (int)(gid - (long long)b * half);
  const int j0 = jp * 2;
  const int j1 = j0 + 1;

  const float2* vb = value + (long long)b * nk;
  const int s0 = s_seg[j0], s1 = s_seg[j1];
  const float t0 = s_t[j0], t1 = s_t[j1];

  const float2 a0 = vb[s0], e0 = vb[s0 + 1];
  const float2 a1 = vb[s1], e1 = vb[s1 + 1];

  float4 o;
  o.x = a0.x + (e0.x - a0.x) * t0;
  o.y = a0.y + (e0.y - a0.y) * t0;
  o.z = a1.x + (e1.x - a1.x) * t1;
  o.w = a1.y + (e1.y - a1.y) * t1;
  out[gid] = o;
}

extern "C" void kernel_launch(void* const* d_in, const int* in_sizes, int n_in,
                              void* d_out, int out_size, void* d_ws, size_t ws_size,
                              hipStream_t stream) {
  const int*   index = (const int*)d_in[0];
  const float* value = (const float*)d_in[1];
  float*       out   = (float*)d_out;

  const int nk    = in_sizes[0];                 // 13
  const int batch = in_sizes[1] / (nk * 2);      // 262144
  const int m     = out_size / (batch * 2);      // 48
  const int half  = m / 2;                       // 24 j-pairs per batch

  const long long total = (long long)batch * half;  // threads
  const int block = 256;
  const int grid  = (int)((total + block - 1) / block);

  LinearInterpolation_20907900797406_kernel<<<grid, block, 0, stream>>>(
      index, (const float2*)value, (float4*)out, batch, nk, m);
}

// Round 2
// 128.679 us; speedup vs baseline: 1.0896x; 1.0896x over previous
//
#include <hip/hip_runtime.h>

// LinearInterpolation: out[b, j, c] = lerp(v[b,seg[j],c], v[b,seg[j]+1,c], t[j])
// seg/t derived from the tiny knot array (13 ints). BATCH=262144, M=48, C=2.
//
// Memory-bound: 100.7 MB write + 27.3 MB read -> ~20 us at 6.3 TB/s.
// Block = 256 threads owns 64 whole batches:
//   1) coalesced float4 staging of the 64 batches' value rows (6656 B) to LDS
//   2) compute from LDS, perfectly-contiguous float4 stores (6 per thread)

#define BPB 64  // batches per block

__global__ __launch_bounds__(256)
void LinearInterpolation_20907900797406_kernel(
    const int* __restrict__ index,
    const float* __restrict__ value,
    float4* __restrict__ out4,
    int batch, int nk, int m) {
  __shared__ int   s_idx[32];
  __shared__ int   s_seg[64];
  __shared__ float s_t[64];
  __shared__ float s_val[BPB * 32];  // supports nk up to 16 (2*nk floats/batch)

  const int tid = threadIdx.x;
  if (tid < nk) s_idx[tid] = index[tid];
  __syncthreads();
  if (tid < m) {
    // p = idx[0] + tid + 1; seg = (#knots < p) - 1  (searchsorted left - 1)
    const int p = s_idx[0] + tid + 1;
    int cnt = 0;
    #pragma unroll 13
    for (int k = 0; k < nk; ++k) cnt += (s_idx[k] < p) ? 1 : 0;
    const int seg = cnt - 1;
    s_seg[tid] = seg;
    s_t[tid] = (float)(p - s_idx[seg]) / (float)(s_idx[seg + 1] - s_idx[seg]);
  }

  // Stage this block's value rows into LDS with coalesced float4 loads.
  // Block's slice starts at batch b0, byte offset b0*nk*8 (16B-aligned for
  // BPB=64), length nb*nk*2 floats.
  const int b0 = blockIdx.x * BPB;
  const int nb = min(BPB, batch - b0);
  const int nfl = nb * nk * 2;          // floats this block
  const int nf4 = nfl >> 2;             // full float4s
  const float4* src4 = (const float4*)(value + (long long)b0 * nk * 2);
  float4* s_val4 = (float4*)s_val;
  for (int i = tid; i < nf4; i += 256) s_val4[i] = src4[i];
  if (tid < (nfl & 3)) {                // tail floats (only possible last block)
    s_val[(nf4 << 2) + tid] = value[(long long)b0 * nk * 2 + (nf4 << 2) + tid];
  }
  __syncthreads();

  // Compute + contiguous float4 stores.
  const int half = m >> 1;                       // float4s per batch (24)
  const int npairs = nb * half;                  // this block's float4 count
  const long long outBase = (long long)b0 * half;
  const int row = nk * 2;                        // floats per batch in LDS
  for (int off = tid; off < npairs; off += 256) {
    const int bl = off / half;
    const int jp = off - bl * half;
    const float* vb = &s_val[bl * row];
    const int j0 = jp * 2;
    const int sa = s_seg[j0], sb = s_seg[j0 + 1];
    const float ta = s_t[j0], tb = s_t[j0 + 1];
    const float2 a0 = *(const float2*)&vb[2 * sa];
    const float2 e0 = *(const float2*)&vb[2 * sa + 2];
    const float2 a1 = *(const float2*)&vb[2 * sb];
    const float2 e1 = *(const float2*)&vb[2 * sb + 2];
    float4 o;
    o.x = a0.x + (e0.x - a0.x) * ta;
    o.y = a0.y + (e0.y - a0.y) * ta;
    o.z = a1.x + (e1.x - a1.x) * tb;
    o.w = a1.y + (e1.y - a1.y) * tb;
    out4[outBase + off] = o;
  }
}

extern "C" void kernel_launch(void* const* d_in, const int* in_sizes, int n_in,
                              void* d_out, int out_size, void* d_ws, size_t ws_size,
                              hipStream_t stream) {
  const int*   index = (const int*)d_in[0];
  const float* value = (const float*)d_in[1];
  float*       out   = (float*)d_out;

  const int nk    = in_sizes[0];             // 13
  const int batch = in_sizes[1] / (nk * 2);  // 262144
  const int m     = out_size / (batch * 2);  // 48

  const int grid = (batch + BPB - 1) / BPB;  // 4096 blocks
  LinearInterpolation_20907900797406_kernel<<<grid, 256, 0, stream>>>(
      index, value, (float4*)out, batch, nk, m);
}